// Round 8
// baseline (179.346 us; speedup 1.0000x reference)
//
#include <hip/hip_runtime.h>

constexpr int PPB = 16;  // consecutive points per block (8192 blocks)
constexpr int N56 = 56*56*64;    // 200704
constexpr int N28 = 28*28*128;   // 100352
constexpr int N14 = 14*14*256;   //  50176
constexpr int N7  = 7*7*512;     //  25088
constexpr int NTOT = N56 + N28 + N14 + N7;      // 376320 (x2B = 752640, /256 exact)
constexpr int CONV_BLOCKS  = (NTOT + 255) / 256; // 1470
constexpr size_t PRM_OFF   = (size_t)NTOT * 2;   // params start in d_ws (16B-aligned)

typedef float    f4v __attribute__((ext_vector_type(4)));
typedef _Float16 h4v __attribute__((ext_vector_type(4)));

// ---------- phase 1: convert feats to fp16 + per-point/level params ----------
__device__ inline void mk_level(float h, float w, float inv, int H, int C,
                                int4* off, f4v* wgt) {
    const float x = h * inv, y = w * inv;
    const float x1 = floorf(x), x2 = ceilf(x);
    const float y1 = floorf(y), y2 = ceilf(y);
    const int xi1 = min(max((int)x1, 0), H - 1);
    const int xi2 = min(max((int)x2, 0), H - 1);
    const int yi1 = min(max((int)y1, 0), H - 1);
    const int yi2 = min(max((int)y2, 0), H - 1);
    off->x = (xi1 * H + yi1) * C;
    off->y = (xi2 * H + yi1) * C;
    off->z = (xi1 * H + yi2) * C;
    off->w = (xi2 * H + yi2) * C;
    wgt->x = (x2 - x) * (y2 - y);
    wgt->y = (x - x1) * (y2 - y);
    wgt->z = (x2 - x) * (y - y1);
    wgt->w = (x - x1) * (y - y1);
}

__global__ __launch_bounds__(256) void prep_kernel(
    const float* __restrict__ coord,
    const float* __restrict__ f56, const float* __restrict__ f28,
    const float* __restrict__ f14, const float* __restrict__ f7,
    _Float16* __restrict__ ws, char* __restrict__ prm, int n)
{
    const int b = blockIdx.x;
    if (b < CONV_BLOCKS) {
        int idx = b * 256 + threadIdx.x;
        if (idx >= NTOT) return;
        float v;
        if (idx < N56)              v = f56[idx];
        else if (idx < N56+N28)     v = f28[idx - N56];
        else if (idx < N56+N28+N14) v = f14[idx - (N56+N28)];
        else                        v = f7[idx - (N56+N28+N14)];
        ws[idx] = (_Float16)v;
    } else {
        int p = (b - CONV_BLOCKS) * 256 + threadIdx.x;
        if (p >= n) return;
        const float X = coord[p*3+0], Y = coord[p*3+1], Z = coord[p*3+2];
        const float rz = 1.0f / (-Z);
        float h = 250.0f * (-Y) * rz + 112.0f;
        float w = 250.0f * X  * rz + 112.0f;
        h = fminf(fmaxf(h, 0.0f), 223.0f);
        w = fminf(fmaxf(w, 0.0f), 223.0f);
        char* pb = prm + (size_t)p * 128;
        int4 o; f4v g;
        mk_level(h, w, 0.25f,    56, 64,  &o, &g);
        *reinterpret_cast<int4*>(pb +  0) = o; *reinterpret_cast<f4v*>(pb + 16) = g;
        mk_level(h, w, 0.125f,   28, 128, &o, &g);
        *reinterpret_cast<int4*>(pb + 32) = o; *reinterpret_cast<f4v*>(pb + 48) = g;
        mk_level(h, w, 0.0625f,  14, 256, &o, &g);
        *reinterpret_cast<int4*>(pb + 64) = o; *reinterpret_cast<f4v*>(pb + 80) = g;
        mk_level(h, w, 0.03125f,  7, 512, &o, &g);
        *reinterpret_cast<int4*>(pb + 96) = o; *reinterpret_cast<f4v*>(pb + 112) = g;
    }
}

// ---------- phase 2: slim gather kernel ----------
__global__ __launch_bounds__(256) void GraphProjection_57483842289710_kernel(
    const float* __restrict__ coord,
    const _Float16* __restrict__ ws,
    const char* __restrict__ prm,
    float* __restrict__ out, int n)
{
    const int t = threadIdx.x;
    const int ch = 4 * t;
    const _Float16* f; int lvl;
    if (ch < 64)       { f = ws + ch;                       lvl = 0; }
    else if (ch < 192) { f = ws + N56 + (ch - 64);          lvl = 1; }
    else if (ch < 448) { f = ws + N56+N28 + (ch - 192);     lvl = 2; }
    else               { f = ws + N56+N28+N14 + (ch - 448); lvl = 3; }
    const size_t poff = (size_t)lvl * 32;

    const int p0 = blockIdx.x * PPB;
    const int pend = min(p0 + PPB, n);

    #pragma unroll 2
    for (int p = p0; p < pend; ++p) {
        float* __restrict__ orow = out + (size_t)p * 963;
        if (t < 240) {
            const char* pb = prm + (size_t)p * 128 + poff;
            const int4 o  = *reinterpret_cast<const int4*>(pb);
            const f4v wg  = *reinterpret_cast<const f4v*>(pb + 16);

            const h4v a = *reinterpret_cast<const h4v*>(f + o.x);
            const h4v b = *reinterpret_cast<const h4v*>(f + o.y);
            const h4v d = *reinterpret_cast<const h4v*>(f + o.z);
            const h4v e = *reinterpret_cast<const h4v*>(f + o.w);

            f4v r;
            r.x = wg.x*(float)a.x + wg.y*(float)b.x + wg.z*(float)d.x + wg.w*(float)e.x;
            r.y = wg.x*(float)a.y + wg.y*(float)b.y + wg.z*(float)d.y + wg.w*(float)e.y;
            r.z = wg.x*(float)a.z + wg.y*(float)b.z + wg.z*(float)d.z + wg.w*(float)e.z;
            r.w = wg.x*(float)a.w + wg.y*(float)b.w + wg.z*(float)d.w + wg.w*(float)e.w;
            *reinterpret_cast<f4v*>(orow + 3 + ch) = r;
        } else if (t < 243) {
            orow[t - 240] = coord[p * 3 + (t - 240)];
        }
    }
}

// ---------- fallback A: round-7 winner (fp16, inline setup) ----------
__global__ __launch_bounds__(256) void proj_f16_inline_kernel(
    const float* __restrict__ coord, const _Float16* __restrict__ ws,
    float* __restrict__ out, int n)
{
    const int t = threadIdx.x;
    const int ch = 4 * t;
    const _Float16* f; int C, H; float inv;
    if (ch < 64)       { f = ws + ch;                     C = 64;  H = 56; inv = 0.25f;    }
    else if (ch < 192) { f = ws + N56 + (ch - 64);        C = 128; H = 28; inv = 0.125f;   }
    else if (ch < 448) { f = ws + N56+N28 + (ch - 192);   C = 256; H = 14; inv = 0.0625f;  }
    else               { f = ws + N56+N28+N14 + (ch-448); C = 512; H = 7;  inv = 0.03125f; }
    const int p0 = blockIdx.x * PPB, pend = min(p0 + PPB, n);
    #pragma unroll 2
    for (int p = p0; p < pend; ++p) {
        float* __restrict__ orow = out + (size_t)p * 963;
        const float X = coord[p*3+0], Y = coord[p*3+1], Z = coord[p*3+2];
        const float rz = 1.0f / (-Z);
        float h = 250.0f * (-Y) * rz + 112.0f;
        float w = 250.0f * X  * rz + 112.0f;
        h = fminf(fmaxf(h, 0.0f), 223.0f);
        w = fminf(fmaxf(w, 0.0f), 223.0f);
        if (t < 240) {
            const float x = h * inv, y = w * inv;
            const float x1 = floorf(x), x2 = ceilf(x);
            const float y1 = floorf(y), y2 = ceilf(y);
            const int xi1 = min(max((int)x1, 0), H - 1);
            const int xi2 = min(max((int)x2, 0), H - 1);
            const int yi1 = min(max((int)y1, 0), H - 1);
            const int yi2 = min(max((int)y2, 0), H - 1);
            const float w11 = (x2-x)*(y2-y), w21 = (x-x1)*(y2-y);
            const float w12 = (x2-x)*(y-y1), w22 = (x-x1)*(y-y1);
            const int r1 = xi1*H, r2 = xi2*H;
            const h4v a = *reinterpret_cast<const h4v*>(f + (r1+yi1)*C);
            const h4v b = *reinterpret_cast<const h4v*>(f + (r2+yi1)*C);
            const h4v d = *reinterpret_cast<const h4v*>(f + (r1+yi2)*C);
            const h4v e = *reinterpret_cast<const h4v*>(f + (r2+yi2)*C);
            f4v r;
            r.x = w11*(float)a.x + w21*(float)b.x + w12*(float)d.x + w22*(float)e.x;
            r.y = w11*(float)a.y + w21*(float)b.y + w12*(float)d.y + w22*(float)e.y;
            r.z = w11*(float)a.z + w21*(float)b.z + w12*(float)d.z + w22*(float)e.z;
            r.w = w11*(float)a.w + w21*(float)b.w + w12*(float)d.w + w22*(float)e.w;
            *reinterpret_cast<f4v*>(orow + 3 + ch) = r;
        } else if (t < 243) {
            orow[t - 240] = coord[p*3 + (t-240)];
        }
    }
}

// convert-only kernel for fallback A
__global__ __launch_bounds__(256) void convert_feats_kernel(
    const float* __restrict__ f56, const float* __restrict__ f28,
    const float* __restrict__ f14, const float* __restrict__ f7,
    _Float16* __restrict__ ws)
{
    int idx = blockIdx.x * 256 + threadIdx.x;
    if (idx >= NTOT) return;
    float v;
    if (idx < N56)              v = f56[idx];
    else if (idx < N56+N28)     v = f28[idx - N56];
    else if (idx < N56+N28+N14) v = f14[idx - (N56+N28)];
    else                        v = f7[idx - (N56+N28+N14)];
    ws[idx] = (_Float16)v;
}

// ---------- fallback B: fp32 (round-4 winner) ----------
__global__ __launch_bounds__(256) void proj_f32_kernel(
    const float* __restrict__ coord,
    const float* __restrict__ f56, const float* __restrict__ f28,
    const float* __restrict__ f14, const float* __restrict__ f7,
    float* __restrict__ out, int n)
{
    const int t = threadIdx.x;
    const int ch = 4 * t;
    const float* f; int C, H; float inv;
    if (ch < 64)       { f = f56 + ch;         C = 64;  H = 56; inv = 0.25f;    }
    else if (ch < 192) { f = f28 + (ch - 64);  C = 128; H = 28; inv = 0.125f;   }
    else if (ch < 448) { f = f14 + (ch - 192); C = 256; H = 14; inv = 0.0625f;  }
    else               { f = f7  + (ch - 448); C = 512; H = 7;  inv = 0.03125f; }
    const int p0 = blockIdx.x * PPB, pend = min(p0 + PPB, n);
    #pragma unroll 2
    for (int p = p0; p < pend; ++p) {
        float* __restrict__ orow = out + (size_t)p * 963;
        const float X = coord[p*3+0], Y = coord[p*3+1], Z = coord[p*3+2];
        const float rz = 1.0f / (-Z);
        float h = 250.0f * (-Y) * rz + 112.0f;
        float w = 250.0f * X  * rz + 112.0f;
        h = fminf(fmaxf(h, 0.0f), 223.0f);
        w = fminf(fmaxf(w, 0.0f), 223.0f);
        if (t < 240) {
            const float x = h * inv, y = w * inv;
            const float x1 = floorf(x), x2 = ceilf(x);
            const float y1 = floorf(y), y2 = ceilf(y);
            const int xi1 = min(max((int)x1, 0), H - 1);
            const int xi2 = min(max((int)x2, 0), H - 1);
            const int yi1 = min(max((int)y1, 0), H - 1);
            const int yi2 = min(max((int)y2, 0), H - 1);
            const float w11 = (x2-x)*(y2-y), w21 = (x-x1)*(y2-y);
            const float w12 = (x2-x)*(y-y1), w22 = (x-x1)*(y-y1);
            const int r1 = xi1*H, r2 = xi2*H;
            const float4 a = *reinterpret_cast<const float4*>(f + (r1+yi1)*C);
            const float4 b = *reinterpret_cast<const float4*>(f + (r2+yi1)*C);
            const float4 d = *reinterpret_cast<const float4*>(f + (r1+yi2)*C);
            const float4 e = *reinterpret_cast<const float4*>(f + (r2+yi2)*C);
            f4v r;
            r.x = w11*a.x + w21*b.x + w12*d.x + w22*e.x;
            r.y = w11*a.y + w21*b.y + w12*d.y + w22*e.y;
            r.z = w11*a.z + w21*b.z + w12*d.z + w22*e.z;
            r.w = w11*a.w + w21*b.w + w12*d.w + w22*e.w;
            *reinterpret_cast<f4v*>(orow + 3 + ch) = r;
        } else if (t < 243) {
            orow[t - 240] = coord[p*3 + (t-240)];
        }
    }
}

extern "C" void kernel_launch(void* const* d_in, const int* in_sizes, int n_in,
                              void* d_out, int out_size, void* d_ws, size_t ws_size,
                              hipStream_t stream) {
    const float* coord = (const float*)d_in[0];
    const float* f56   = (const float*)d_in[1];
    const float* f28   = (const float*)d_in[2];
    const float* f14   = (const float*)d_in[3];
    const float* f7    = (const float*)d_in[4];
    float* out = (float*)d_out;

    int n = in_sizes[0] / 3;  // 131072 points
    int grid = (n + PPB - 1) / PPB;

    const size_t need_full = PRM_OFF + (size_t)n * 128;
    if (ws_size >= need_full) {
        _Float16* ws = (_Float16*)d_ws;
        char* prm = (char*)d_ws + PRM_OFF;
        int param_blocks = (n + 255) / 256;
        prep_kernel<<<CONV_BLOCKS + param_blocks, 256, 0, stream>>>(
            coord, f56, f28, f14, f7, ws, prm, n);
        GraphProjection_57483842289710_kernel<<<grid, 256, 0, stream>>>(
            coord, ws, prm, out, n);
    } else if (ws_size >= (size_t)NTOT * sizeof(_Float16)) {
        _Float16* ws = (_Float16*)d_ws;
        convert_feats_kernel<<<CONV_BLOCKS, 256, 0, stream>>>(f56, f28, f14, f7, ws);
        proj_f16_inline_kernel<<<grid, 256, 0, stream>>>(coord, ws, out, n);
    } else {
        proj_f32_kernel<<<grid, 256, 0, stream>>>(coord, f56, f28, f14, f7, out, n);
    }
}

// Round 9
// 150.021 us; speedup vs baseline: 1.1955x; 1.1955x over previous
//
#include <hip/hip_runtime.h>

constexpr int PPB = 16;  // consecutive points per block (8192 blocks)
constexpr int N56 = 56*56*64;    // 200704
constexpr int N28 = 28*28*128;   // 100352
constexpr int N14 = 14*14*256;   //  50176
constexpr int N7  = 7*7*512;     //  25088
constexpr int NTOT = N56 + N28 + N14 + N7;       // 376320
constexpr int CONV_BLOCKS = (NTOT + 255) / 256;  // 1470

typedef float    f4v __attribute__((ext_vector_type(4)));
typedef _Float16 h4v __attribute__((ext_vector_type(4)));

// ---- fp32 features -> fp16 in d_ws ----
__global__ __launch_bounds__(256) void convert_feats_kernel(
    const float* __restrict__ f56, const float* __restrict__ f28,
    const float* __restrict__ f14, const float* __restrict__ f7,
    _Float16* __restrict__ ws)
{
    int idx = blockIdx.x * 256 + threadIdx.x;
    if (idx >= NTOT) return;
    float v;
    if (idx < N56)              v = f56[idx];
    else if (idx < N56+N28)     v = f28[idx - N56];
    else if (idx < N56+N28+N14) v = f14[idx - (N56+N28)];
    else                        v = f7[idx - (N56+N28+N14)];
    ws[idx] = (_Float16)v;
}

// one point's bilinear sample for this thread's channel quad
__device__ __forceinline__ f4v samp(float X, float Y, float Z,
                                    const _Float16* __restrict__ f,
                                    float inv, int H, int C)
{
    const float rz = 1.0f / (-Z);
    float h = 250.0f * (-Y) * rz + 112.0f;
    float w = 250.0f * X  * rz + 112.0f;
    h = fminf(fmaxf(h, 0.0f), 223.0f);
    w = fminf(fmaxf(w, 0.0f), 223.0f);
    const float x = h * inv, y = w * inv;
    const float x1 = floorf(x), x2 = ceilf(x);
    const float y1 = floorf(y), y2 = ceilf(y);
    const int xi1 = min(max((int)x1, 0), H - 1);
    const int xi2 = min(max((int)x2, 0), H - 1);
    const int yi1 = min(max((int)y1, 0), H - 1);
    const int yi2 = min(max((int)y2, 0), H - 1);
    const float w11 = (x2 - x) * (y2 - y);
    const float w21 = (x - x1) * (y2 - y);
    const float w12 = (x2 - x) * (y - y1);
    const float w22 = (x - x1) * (y - y1);
    const int r1 = xi1 * H, r2 = xi2 * H;
    const h4v a = *reinterpret_cast<const h4v*>(f + (r1 + yi1) * C);
    const h4v b = *reinterpret_cast<const h4v*>(f + (r2 + yi1) * C);
    const h4v d = *reinterpret_cast<const h4v*>(f + (r1 + yi2) * C);
    const h4v e = *reinterpret_cast<const h4v*>(f + (r2 + yi2) * C);
    f4v r;
    r.x = w11*(float)a.x + w21*(float)b.x + w12*(float)d.x + w22*(float)e.x;
    r.y = w11*(float)a.y + w21*(float)b.y + w12*(float)d.y + w22*(float)e.y;
    r.z = w11*(float)a.z + w21*(float)b.z + w12*(float)d.z + w22*(float)e.z;
    r.w = w11*(float)a.w + w21*(float)b.w + w12*(float)d.w + w22*(float)e.w;
    return r;
}

// ---- hot kernel: 4 points per iteration, independent chains (ILP=4) ----
__global__ __launch_bounds__(256) void GraphProjection_57483842289710_kernel(
    const float* __restrict__ coord,
    const _Float16* __restrict__ ws,
    float* __restrict__ out, int n)
{
    const int t = threadIdx.x;
    const int ch = 4 * t;
    const _Float16* f; int C, H; float inv;
    if (ch < 64)       { f = ws + ch;                     C = 64;  H = 56; inv = 0.25f;    }
    else if (ch < 192) { f = ws + N56 + (ch - 64);        C = 128; H = 28; inv = 0.125f;   }
    else if (ch < 448) { f = ws + N56+N28 + (ch - 192);   C = 256; H = 14; inv = 0.0625f;  }
    else               { f = ws + N56+N28+N14 + (ch-448); C = 512; H = 7;  inv = 0.03125f; }

    const int p0 = blockIdx.x * PPB;

    #pragma unroll 1
    for (int k = 0; k < PPB; k += 4) {
        const int p = p0 + k;
        if (p + 3 >= n) break;  // n % 16 == 0 in practice; safety only

        // 4 points' coords = 3 aligned float4 loads (p*3 is a multiple of 12;
        // block base p0*3 = blockIdx*48 floats -> 16B aligned)
        const f4v c0 = *reinterpret_cast<const f4v*>(coord + (size_t)p * 3 + 0);
        const f4v c1 = *reinterpret_cast<const f4v*>(coord + (size_t)p * 3 + 4);
        const f4v c2 = *reinterpret_cast<const f4v*>(coord + (size_t)p * 3 + 8);

        float* o = out + (size_t)p * 963;
        if (t < 240) {
            // four fully independent chains -> scheduler overlaps the 16
            // gather loads' latency
            f4v r0 = samp(c0.x, c0.y, c0.z, f, inv, H, C);
            f4v r1 = samp(c0.w, c1.x, c1.y, f, inv, H, C);
            f4v r2 = samp(c1.z, c1.w, c2.x, f, inv, H, C);
            f4v r3 = samp(c2.y, c2.z, c2.w, f, inv, H, C);
            float* oc = o + 3 + ch;
            *reinterpret_cast<f4v*>(oc +    0) = r0;
            *reinterpret_cast<f4v*>(oc +  963) = r1;
            *reinterpret_cast<f4v*>(oc + 1926) = r2;
            *reinterpret_cast<f4v*>(oc + 2889) = r3;
        } else if (t < 243) {
            const int j = t - 240;
            o[j +    0] = coord[(size_t)(p + 0) * 3 + j];
            o[j +  963] = coord[(size_t)(p + 1) * 3 + j];
            o[j + 1926] = coord[(size_t)(p + 2) * 3 + j];
            o[j + 2889] = coord[(size_t)(p + 3) * 3 + j];
        }
    }
}

// ---- fp32 fallback (round-4 winner) if ws too small ----
__global__ __launch_bounds__(256) void proj_f32_kernel(
    const float* __restrict__ coord,
    const float* __restrict__ f56, const float* __restrict__ f28,
    const float* __restrict__ f14, const float* __restrict__ f7,
    float* __restrict__ out, int n)
{
    const int t = threadIdx.x;
    const int ch = 4 * t;
    const float* f; int C, H; float inv;
    if (ch < 64)       { f = f56 + ch;         C = 64;  H = 56; inv = 0.25f;    }
    else if (ch < 192) { f = f28 + (ch - 64);  C = 128; H = 28; inv = 0.125f;   }
    else if (ch < 448) { f = f14 + (ch - 192); C = 256; H = 14; inv = 0.0625f;  }
    else               { f = f7  + (ch - 448); C = 512; H = 7;  inv = 0.03125f; }
    const int p0 = blockIdx.x * PPB, pend = min(p0 + PPB, n);
    #pragma unroll 2
    for (int p = p0; p < pend; ++p) {
        float* __restrict__ orow = out + (size_t)p * 963;
        const float X = coord[p*3+0], Y = coord[p*3+1], Z = coord[p*3+2];
        const float rz = 1.0f / (-Z);
        float h = 250.0f * (-Y) * rz + 112.0f;
        float w = 250.0f * X  * rz + 112.0f;
        h = fminf(fmaxf(h, 0.0f), 223.0f);
        w = fminf(fmaxf(w, 0.0f), 223.0f);
        if (t < 240) {
            const float x = h * inv, y = w * inv;
            const float x1 = floorf(x), x2 = ceilf(x);
            const float y1 = floorf(y), y2 = ceilf(y);
            const int xi1 = min(max((int)x1, 0), H - 1);
            const int xi2 = min(max((int)x2, 0), H - 1);
            const int yi1 = min(max((int)y1, 0), H - 1);
            const int yi2 = min(max((int)y2, 0), H - 1);
            const float w11 = (x2-x)*(y2-y), w21 = (x-x1)*(y2-y);
            const float w12 = (x2-x)*(y-y1), w22 = (x-x1)*(y-y1);
            const int r1 = xi1*H, r2 = xi2*H;
            const float4 a = *reinterpret_cast<const float4*>(f + (r1+yi1)*C);
            const float4 b = *reinterpret_cast<const float4*>(f + (r2+yi1)*C);
            const float4 d = *reinterpret_cast<const float4*>(f + (r1+yi2)*C);
            const float4 e = *reinterpret_cast<const float4*>(f + (r2+yi2)*C);
            f4v r;
            r.x = w11*a.x + w21*b.x + w12*d.x + w22*e.x;
            r.y = w11*a.y + w21*b.y + w12*d.y + w22*e.y;
            r.z = w11*a.z + w21*b.z + w12*d.z + w22*e.z;
            r.w = w11*a.w + w21*b.w + w12*d.w + w22*e.w;
            *reinterpret_cast<f4v*>(orow + 3 + ch) = r;
        } else if (t < 243) {
            orow[t - 240] = coord[p*3 + (t-240)];
        }
    }
}

extern "C" void kernel_launch(void* const* d_in, const int* in_sizes, int n_in,
                              void* d_out, int out_size, void* d_ws, size_t ws_size,
                              hipStream_t stream) {
    const float* coord = (const float*)d_in[0];
    const float* f56   = (const float*)d_in[1];
    const float* f28   = (const float*)d_in[2];
    const float* f14   = (const float*)d_in[3];
    const float* f7    = (const float*)d_in[4];
    float* out = (float*)d_out;

    int n = in_sizes[0] / 3;  // 131072 points
    int grid = (n + PPB - 1) / PPB;

    if (ws_size >= (size_t)NTOT * sizeof(_Float16)) {
        _Float16* ws = (_Float16*)d_ws;
        convert_feats_kernel<<<CONV_BLOCKS, 256, 0, stream>>>(f56, f28, f14, f7, ws);
        GraphProjection_57483842289710_kernel<<<grid, 256, 0, stream>>>(coord, ws, out, n);
    } else {
        proj_f32_kernel<<<grid, 256, 0, stream>>>(coord, f56, f28, f14, f7, out, n);
    }
}

// Round 10
// 139.720 us; speedup vs baseline: 1.2836x; 1.0737x over previous
//
#include <hip/hip_runtime.h>

constexpr int PPB = 16;  // consecutive points per block (8192 blocks)
constexpr int N56 = 56*56*64;    // 200704
constexpr int N28 = 28*28*128;   // 100352
constexpr int N14 = 14*14*256;   //  50176
constexpr int N7  = 7*7*512;     //  25088
constexpr int NTOT = N56 + N28 + N14 + N7;       // 376320
constexpr int CONV_BLOCKS = (NTOT + 255) / 256;  // 1470

typedef float    f4v __attribute__((ext_vector_type(4)));
typedef float    f8v __attribute__((ext_vector_type(8)));
typedef _Float16 h8v __attribute__((ext_vector_type(8)));

// ---- fp32 features -> fp16 in d_ws ----
__global__ __launch_bounds__(256) void convert_feats_kernel(
    const float* __restrict__ f56, const float* __restrict__ f28,
    const float* __restrict__ f14, const float* __restrict__ f7,
    _Float16* __restrict__ ws)
{
    int idx = blockIdx.x * 256 + threadIdx.x;
    if (idx >= NTOT) return;
    float v;
    if (idx < N56)              v = f56[idx];
    else if (idx < N56+N28)     v = f28[idx - N56];
    else if (idx < N56+N28+N14) v = f14[idx - (N56+N28)];
    else                        v = f7[idx - (N56+N28+N14)];
    ws[idx] = (_Float16)v;
}

// ---- hot kernel: 128 threads/block, 8 channels/thread ----
__global__ __launch_bounds__(128) void GraphProjection_57483842289710_kernel(
    const float* __restrict__ coord,
    const _Float16* __restrict__ ws,
    float* __restrict__ out, int n)
{
    const int t = threadIdx.x;
    const int ch = 8 * t;                 // channels ch..ch+7 (960 = 120*8)
    const _Float16* f; int C, H; float inv;
    if (t < 8)        { f = ws + ch;                     C = 64;  H = 56; inv = 0.25f;    }
    else if (t < 24)  { f = ws + N56 + (ch - 64);        C = 128; H = 28; inv = 0.125f;   }
    else if (t < 56)  { f = ws + N56+N28 + (ch - 192);   C = 256; H = 14; inv = 0.0625f;  }
    else              { f = ws + N56+N28+N14 + (ch-448); C = 512; H = 7;  inv = 0.03125f; }

    const int p0 = blockIdx.x * PPB;
    const int pend = min(p0 + PPB, n);

    #pragma unroll 2
    for (int p = p0; p < pend; ++p) {
        float* __restrict__ orow = out + (size_t)p * 963;

        const float X = coord[p * 3 + 0];
        const float Y = coord[p * 3 + 1];
        const float Z = coord[p * 3 + 2];

        const float rz = 1.0f / (-Z);
        float h = 250.0f * (-Y) * rz + 112.0f;
        float w = 250.0f * X  * rz + 112.0f;
        h = fminf(fmaxf(h, 0.0f), 223.0f);
        w = fminf(fmaxf(w, 0.0f), 223.0f);

        if (t < 120) {
            const float x = h * inv, y = w * inv;
            const float x1 = floorf(x), x2 = ceilf(x);
            const float y1 = floorf(y), y2 = ceilf(y);
            const int xi1 = min(max((int)x1, 0), H - 1);
            const int xi2 = min(max((int)x2, 0), H - 1);
            const int yi1 = min(max((int)y1, 0), H - 1);
            const int yi2 = min(max((int)y2, 0), H - 1);
            const float w11 = (x2 - x) * (y2 - y);
            const float w21 = (x - x1) * (y2 - y);
            const float w12 = (x2 - x) * (y - y1);
            const float w22 = (x - x1) * (y - y1);

            const int r1 = xi1 * H, r2 = xi2 * H;
            // 16B-aligned fp16 octo loads (ch multiple of 8 -> 16B offsets)
            const h8v a = *reinterpret_cast<const h8v*>(f + (r1 + yi1) * C);
            const h8v b = *reinterpret_cast<const h8v*>(f + (r2 + yi1) * C);
            const h8v d = *reinterpret_cast<const h8v*>(f + (r1 + yi2) * C);
            const h8v e = *reinterpret_cast<const h8v*>(f + (r2 + yi2) * C);

            const f8v r = w11 * __builtin_convertvector(a, f8v)
                        + w21 * __builtin_convertvector(b, f8v)
                        + w12 * __builtin_convertvector(d, f8v)
                        + w22 * __builtin_convertvector(e, f8v);

            // 32B span, 4B-aligned: compiler emits two global_store_dwordx4
            *reinterpret_cast<f8v*>(orow + 3 + ch) = r;
        } else if (t < 123) {
            orow[t - 120] = coord[p * 3 + (t - 120)];
        }
    }
}

// ---- fp32 fallback (round-4 winner) if ws too small ----
__global__ __launch_bounds__(256) void proj_f32_kernel(
    const float* __restrict__ coord,
    const float* __restrict__ f56, const float* __restrict__ f28,
    const float* __restrict__ f14, const float* __restrict__ f7,
    float* __restrict__ out, int n)
{
    const int t = threadIdx.x;
    const int ch = 4 * t;
    const float* f; int C, H; float inv;
    if (ch < 64)       { f = f56 + ch;         C = 64;  H = 56; inv = 0.25f;    }
    else if (ch < 192) { f = f28 + (ch - 64);  C = 128; H = 28; inv = 0.125f;   }
    else if (ch < 448) { f = f14 + (ch - 192); C = 256; H = 14; inv = 0.0625f;  }
    else               { f = f7  + (ch - 448); C = 512; H = 7;  inv = 0.03125f; }
    const int p0 = blockIdx.x * PPB, pend = min(p0 + PPB, n);
    #pragma unroll 2
    for (int p = p0; p < pend; ++p) {
        float* __restrict__ orow = out + (size_t)p * 963;
        const float X = coord[p*3+0], Y = coord[p*3+1], Z = coord[p*3+2];
        const float rz = 1.0f / (-Z);
        float h = 250.0f * (-Y) * rz + 112.0f;
        float w = 250.0f * X  * rz + 112.0f;
        h = fminf(fmaxf(h, 0.0f), 223.0f);
        w = fminf(fmaxf(w, 0.0f), 223.0f);
        if (t < 240) {
            const float x = h * inv, y = w * inv;
            const float x1 = floorf(x), x2 = ceilf(x);
            const float y1 = floorf(y), y2 = ceilf(y);
            const int xi1 = min(max((int)x1, 0), H - 1);
            const int xi2 = min(max((int)x2, 0), H - 1);
            const int yi1 = min(max((int)y1, 0), H - 1);
            const int yi2 = min(max((int)y2, 0), H - 1);
            const float w11 = (x2-x)*(y2-y), w21 = (x-x1)*(y2-y);
            const float w12 = (x2-x)*(y-y1), w22 = (x-x1)*(y-y1);
            const int r1 = xi1*H, r2 = xi2*H;
            const float4 a = *reinterpret_cast<const float4*>(f + (r1+yi1)*C);
            const float4 b = *reinterpret_cast<const float4*>(f + (r2+yi1)*C);
            const float4 d = *reinterpret_cast<const float4*>(f + (r1+yi2)*C);
            const float4 e = *reinterpret_cast<const float4*>(f + (r2+yi2)*C);
            f4v r;
            r.x = w11*a.x + w21*b.x + w12*d.x + w22*e.x;
            r.y = w11*a.y + w21*b.y + w12*d.y + w22*e.y;
            r.z = w11*a.z + w21*b.z + w12*d.z + w22*e.z;
            r.w = w11*a.w + w21*b.w + w12*d.w + w22*e.w;
            *reinterpret_cast<f4v*>(orow + 3 + ch) = r;
        } else if (t < 243) {
            orow[t - 240] = coord[p*3 + (t-240)];
        }
    }
}

extern "C" void kernel_launch(void* const* d_in, const int* in_sizes, int n_in,
                              void* d_out, int out_size, void* d_ws, size_t ws_size,
                              hipStream_t stream) {
    const float* coord = (const float*)d_in[0];
    const float* f56   = (const float*)d_in[1];
    const float* f28   = (const float*)d_in[2];
    const float* f14   = (const float*)d_in[3];
    const float* f7    = (const float*)d_in[4];
    float* out = (float*)d_out;

    int n = in_sizes[0] / 3;  // 131072 points
    int grid = (n + PPB - 1) / PPB;

    if (ws_size >= (size_t)NTOT * sizeof(_Float16)) {
        _Float16* ws = (_Float16*)d_ws;
        convert_feats_kernel<<<CONV_BLOCKS, 256, 0, stream>>>(f56, f28, f14, f7, ws);
        GraphProjection_57483842289710_kernel<<<grid, 128, 0, stream>>>(coord, ws, out, n);
    } else {
        proj_f32_kernel<<<grid, 256, 0, stream>>>(coord, f56, f28, f14, f7, out, n);
    }
}